// Round 17
// baseline (83.674 us; speedup 1.0000x reference)
//
#include <hip/hip_runtime.h>

typedef _Float16 f16;
typedef _Float16 f16x2 __attribute__((ext_vector_type(2)));
typedef _Float16 f16x4 __attribute__((ext_vector_type(4)));
typedef _Float16 f16x8 __attribute__((ext_vector_type(8)));
typedef float f32x4 __attribute__((ext_vector_type(4)));
typedef float f32x16 __attribute__((ext_vector_type(16)));

#define NTOK 4096
#define CIN  256
#define C3   768
#define CO   256
#define NH   8
#define DH   32

__device__ __forceinline__ f32x4 mfma16(f16x8 a, f16x8 b, f32x4 c) {
  return __builtin_amdgcn_mfma_f32_16x16x32_f16(a, b, c, 0, 0, 0);
}
__device__ __forceinline__ f32x16 mfma32(f16x8 a, f16x8 b, f32x16 c) {
  return __builtin_amdgcn_mfma_f32_32x32x16_f16(a, b, c, 0, 0, 0);
}

// native 2^x (input already in log2 domain)
__device__ __forceinline__ float fexp2(float x) {
  float r; asm("v_exp_f32 %0, %1" : "=v"(r) : "v"(x)); return r;
}

__device__ __forceinline__ f16x2 cvt_pk(float lo, float hi) {
  return __builtin_bit_cast(f16x2, __builtin_amdgcn_cvt_pkrtz(lo, hi));
}

// RTZ pack for P (r6/r14/r15/r16 passed with this exact pack)
__device__ __forceinline__ f16x8 pack8(float a0, float a1, float a2, float a3,
                                       float a4, float a5, float a6, float a7) {
  f16x2 p0 = cvt_pk(a0, a1);
  f16x2 p1 = cvt_pk(a2, a3);
  f16x2 p2 = cvt_pk(a4, a5);
  f16x2 p3 = cvt_pk(a6, a7);
  f16x4 lo = __builtin_shufflevector(p0, p1, 0, 1, 2, 3);
  f16x4 hi = __builtin_shufflevector(p2, p3, 0, 1, 2, 3);
  return __builtin_shufflevector(lo, hi, 0, 1, 2, 3, 4, 5, 6, 7);
}

// two 8B LDS reads -> one A/B fragment (72B row stride keeps 8B alignment)
__device__ __forceinline__ f16x8 ld8(const f16* p) {
  f16x4 lo = *reinterpret_cast<const f16x4*>(p);
  f16x4 hi = *reinterpret_cast<const f16x4*>(p + 4);
  return __builtin_shufflevector(lo, hi, 0, 1, 2, 3, 4, 5, 6, 7);
}

// ---------------------------------------------------------------------------
// Kernel 1: qkv — SOURCE BYTE-IDENTICAL to round-12 (passing).
// ---------------------------------------------------------------------------
__global__ __launch_bounds__(256) void qkv_kernel(
    const float* __restrict__ x, const float* __restrict__ Wqkv,
    const float* __restrict__ bqkv,
    f16* __restrict__ qbuf, f16* __restrict__ kbuf, f16* __restrict__ vbuf)
{
  __shared__ f16 As[64][36];   // [n][c]
  __shared__ f16 Bs[64][36];   // [j][c]
  const int b  = blockIdx.z;
  const int n0 = blockIdx.x * 64;
  const int j0 = blockIdx.y * 64;
  const int t  = threadIdx.x;
  const int w  = t >> 6;
  const int lane = t & 63;
  const int l16  = lane & 15;
  const int g4   = lane >> 4;
  const int rowi = t & 63;        // staging row (n or j); lane==row => coalesced
  const int cg   = (t >> 6) * 8;  // staging c-offset

  f32x4 acc[4] = {};
  for (int k0 = 0; k0 < CIN; k0 += 32) {
    float av[8], bv[8];
#pragma unroll
    for (int jj = 0; jj < 8; ++jj) {
      av[jj] = x[((size_t)b * CIN + (k0 + cg + jj)) * NTOK + n0 + rowi];
      bv[jj] = Wqkv[(size_t)(k0 + cg + jj) * C3 + j0 + rowi];
    }
    f16x4 alo, ahi, blo, bhi;
#pragma unroll
    for (int jj = 0; jj < 4; ++jj) {
      alo[jj] = (f16)av[jj];  ahi[jj] = (f16)av[jj + 4];
      blo[jj] = (f16)bv[jj];  bhi[jj] = (f16)bv[jj + 4];
    }
    *reinterpret_cast<f16x4*>(&As[rowi][cg])     = alo;
    *reinterpret_cast<f16x4*>(&As[rowi][cg + 4]) = ahi;
    *reinterpret_cast<f16x4*>(&Bs[rowi][cg])     = blo;
    *reinterpret_cast<f16x4*>(&Bs[rowi][cg + 4]) = bhi;
    __syncthreads();
    f16x8 bf = ld8(&Bs[w * 16 + l16][g4 * 8]);
#pragma unroll
    for (int mf = 0; mf < 4; ++mf) {
      f16x8 af = ld8(&As[mf * 16 + l16][g4 * 8]);
      acc[mf] = mfma16(af, bf, acc[mf]);
    }
    __syncthreads();
  }
  const int j  = j0 + w * 16 + l16;
  const int s  = j >> 8;
  const int hh = (j >> 5) & 7;
  const int d  = j & 31;
  const float bias = bqkv[j];
  const float qscale = 0.25503472f;  // log2(e)/sqrt(32)
  const int bh = b * NH + hh;
#pragma unroll
  for (int mf = 0; mf < 4; ++mf) {
#pragma unroll
    for (int r = 0; r < 4; ++r) {
      const int n = n0 + mf * 16 + g4 * 4 + r;
      const float v = acc[mf][r] + bias;
      if (s == 0) {
        qbuf[((size_t)bh * NTOK + n) * DH + d] = (f16)(v * qscale);
      } else if (s == 1) {
        kbuf[((size_t)bh * NTOK + n) * DH + d] = (f16)v;
      } else {
        // tiled + bit-2/3-swapped position
        const int g4p  = ((g4 & 1) << 1) | (g4 >> 1);
        const int tile = (n0 >> 5) + (mf >> 1);
        const int pos  = ((mf & 1) << 4) + g4p * 4 + r;
        vbuf[((size_t)bh * (NTOK / 32) + tile) * (DH * 32) + d * 32 + pos] = (f16)v;
      }
    }
  }
}

// ---------------------------------------------------------------------------
// Kernel 2: flash attention — REGISTER-DIET variant of r16.
// r15/r16 evidence: residency capped at 2 waves/SIMD by ~176-208 regs/wave
// (VGPR 112 + unified-file accs), so VALU/VMEM/MFMA ran serially regardless
// of grid. Diet: (1) no score software-pipeline (QK->exp->PV in-iteration;
// TLP covers instead of ILP), (2) q-half A processed fully then half B (one
// 16-reg score set live), (3) prefetch depth 1. Target ~116 regs -> 4
// waves/SIMD. Per-q-row arithmetic sequence identical to r16 (passing).
// kv-split x4, additive LDS combine, XCD swizzle all kept from r16.
// ---------------------------------------------------------------------------
__global__ __launch_bounds__(256) void attn_kernel(
    const f16* __restrict__ qbuf, const f16* __restrict__ kbuf,
    const f16* __restrict__ vbuf, f16* __restrict__ ao)
{
  __shared__ float po_lds[3][64][33];   // [z-1][q-in-block][d] padded
  __shared__ float pl_lds[3][64];       // [z-1][q-in-block]

  // XCD swizzle: flat id -> XCD gets a contiguous 128-block chunk;
  // 64 consecutive swizzled blocks = one bh (K/V 2x512KB fits 4MB L2).
  const int flat = blockIdx.x + (int)gridDim.x * blockIdx.y;   // 0..1023
  const int nper = ((int)gridDim.x * (int)gridDim.y) >> 3;     // 128
  const int jj   = (flat & 7) * nper + (flat >> 3);
  const int bh = jj >> 6;
  const int q0 = (jj & 63) * 64;
  const int b = bh >> 3, h = bh & 7;
  const int t = threadIdx.x, w = t >> 6, lane = t & 63;
  const int z = w;                      // kv-split index 0..3
  const int l32 = lane & 31, hi = lane >> 5;
  const size_t kbase = (size_t)bh * NTOK * DH;

  const int qrowA = q0 + l32;
  const int qrowB = qrowA + 32;
  const f16* qpA = qbuf + kbase + (size_t)qrowA * DH + hi * 8;
  const f16* qpB = qbuf + kbase + (size_t)qrowB * DH + hi * 8;
  const f16x8 qfA0 = *reinterpret_cast<const f16x8*>(qpA);
  const f16x8 qfA1 = *reinterpret_cast<const f16x8*>(qpA + 16);
  const f16x8 qfB0 = *reinterpret_cast<const f16x8*>(qpB);
  const f16x8 qfB1 = *reinterpret_cast<const f16x8*>(qpB + 16);

  const size_t zoff = (size_t)z * 32768;   // 32 tiles * 1024 elems
  const f16* kp = kbuf + kbase + zoff + (size_t)l32 * DH + hi * 8;
  const f16* vp = vbuf + kbase + zoff + (size_t)l32 * 32 + hi * 8;

  f32x16 oaccA = {}, oaccB = {};
  float lrunA = 0.f, lrunB = 0.f;
  const f32x16 zero = {};

  // prologue: tile 0 in current regs
  f16x8 kca = *reinterpret_cast<const f16x8*>(kp);
  f16x8 kcb = *reinterpret_cast<const f16x8*>(kp + 16);
  f16x8 vca = *reinterpret_cast<const f16x8*>(vp);
  f16x8 vcb = *reinterpret_cast<const f16x8*>(vp + 16);

  // running prefetch pointers (tile tt+1); tail overrun stays inside d_ws
  const f16* kfut = kp + 1024;
  const f16* vfut = vp + 1024;

#pragma unroll 2
  for (int tt = 0; tt < 32; ++tt) {
    // prefetch tile tt+1 (depth 1; consumed next iteration)
    f16x8 kna = *reinterpret_cast<const f16x8*>(kfut);
    f16x8 knb = *reinterpret_cast<const f16x8*>(kfut + 16);
    f16x8 vna = *reinterpret_cast<const f16x8*>(vfut);
    f16x8 vnb = *reinterpret_cast<const f16x8*>(vfut + 16);
    kfut += 1024; vfut += 1024;

    // ---- q-half A: QK -> exp -> pack -> PV ----
    {
      __builtin_amdgcn_s_setprio(1);
      f32x16 s = mfma32(kca, qfA0, zero);
      s = mfma32(kcb, qfA1, s);
      __builtin_amdgcn_s_setprio(0);
      float e[16];
#pragma unroll
      for (int i = 0; i < 16; ++i) e[i] = fexp2(s[i]);
      float a0 = e[0] + e[1],  a1 = e[2] + e[3];
      float a2 = e[4] + e[5],  a3 = e[6] + e[7];
      float a4 = e[8] + e[9],  a5 = e[10] + e[11];
      float a6 = e[12] + e[13], a7 = e[14] + e[15];
      lrunA += ((a0 + a1) + (a2 + a3)) + ((a4 + a5) + (a6 + a7));
      f16x8 pb0 = pack8(e[0], e[1], e[2], e[3], e[4], e[5], e[6], e[7]);
      f16x8 pb1 = pack8(e[8], e[9], e[10], e[11], e[12], e[13], e[14], e[15]);
      __builtin_amdgcn_s_setprio(1);
      oaccA = mfma32(vca, pb0, oaccA);
      oaccA = mfma32(vcb, pb1, oaccA);
      __builtin_amdgcn_s_setprio(0);
    }

    // ---- q-half B: QK -> exp -> pack -> PV ----
    {
      __builtin_amdgcn_s_setprio(1);
      f32x16 s = mfma32(kca, qfB0, zero);
      s = mfma32(kcb, qfB1, s);
      __builtin_amdgcn_s_setprio(0);
      float e[16];
#pragma unroll
      for (int i = 0; i < 16; ++i) e[i] = fexp2(s[i]);
      float a0 = e[0] + e[1],  a1 = e[2] + e[3];
      float a2 = e[4] + e[5],  a3 = e[6] + e[7];
      float a4 = e[8] + e[9],  a5 = e[10] + e[11];
      float a6 = e[12] + e[13], a7 = e[14] + e[15];
      lrunB += ((a0 + a1) + (a2 + a3)) + ((a4 + a5) + (a6 + a7));
      f16x8 pb0 = pack8(e[0], e[1], e[2], e[3], e[4], e[5], e[6], e[7]);
      f16x8 pb1 = pack8(e[8], e[9], e[10], e[11], e[12], e[13], e[14], e[15]);
      __builtin_amdgcn_s_setprio(1);
      oaccB = mfma32(vca, pb0, oaccB);
      oaccB = mfma32(vcb, pb1, oaccB);
      __builtin_amdgcn_s_setprio(0);
    }

    // rotate current tile registers
    kca = kna; kcb = knb; vca = vna; vcb = vnb;
  }

  // per-half l totals (hi halves combined)
  const float ltotA = lrunA + __shfl_xor(lrunA, 32);
  const float ltotB = lrunB + __shfl_xor(lrunB, 32);

  // z=1..3 waves park raw partials in LDS
  if (z != 0) {
#pragma unroll
    for (int c4 = 0; c4 < 4; ++c4)
#pragma unroll
      for (int r = 0; r < 4; ++r) {
        po_lds[z - 1][l32][hi * 4 + c4 * 8 + r]      = oaccA[c4 * 4 + r];
        po_lds[z - 1][32 + l32][hi * 4 + c4 * 8 + r] = oaccB[c4 * 4 + r];
      }
    if (hi == 0) {
      pl_lds[z - 1][l32]      = ltotA;
      pl_lds[z - 1][32 + l32] = ltotB;
    }
  }
  __syncthreads();

  // z=0 wave combines (additive partials) and stores both q-rows
  if (z == 0) {
    const float invA = 1.0f / (ltotA + pl_lds[0][l32] + pl_lds[1][l32] + pl_lds[2][l32]);
    const float invB = 1.0f / (ltotB + pl_lds[0][32 + l32] + pl_lds[1][32 + l32] + pl_lds[2][32 + l32]);
    f16* aopA = (f16*)ao + ((size_t)b * NTOK + qrowA) * CO + h * DH + hi * 4;
    f16* aopB = (f16*)ao + ((size_t)b * NTOK + qrowB) * CO + h * DH + hi * 4;
#pragma unroll
    for (int c4 = 0; c4 < 4; ++c4) {
      f16x4 stA, stB;
#pragma unroll
      for (int r = 0; r < 4; ++r) {
        const int d = hi * 4 + c4 * 8 + r;
        stA[r] = (f16)((oaccA[c4 * 4 + r] + po_lds[0][l32][d] + po_lds[1][l32][d] + po_lds[2][l32][d]) * invA);
        stB[r] = (f16)((oaccB[c4 * 4 + r] + po_lds[0][32 + l32][d] + po_lds[1][32 + l32][d] + po_lds[2][32 + l32][d]) * invB);
      }
      *reinterpret_cast<f16x4*>(aopA + c4 * 8) = stA;
      *reinterpret_cast<f16x4*>(aopB + c4 * 8) = stB;
    }
  }
}

// ---------------------------------------------------------------------------
// Kernel 3: proj — SOURCE BYTE-IDENTICAL to round-12 (passing).
// ---------------------------------------------------------------------------
__global__ __launch_bounds__(256) void proj_kernel(
    const f16* __restrict__ ao, const float* __restrict__ Wout,
    const float* __restrict__ bout, float* __restrict__ out)
{
  __shared__ f16 Ws[64][36];    // [j][c]
  __shared__ f16 Aos[64][36];   // [n][c]
  const int b  = blockIdx.z;
  const int n0 = blockIdx.x * 64;
  const int j0 = blockIdx.y * 64;
  const int t = threadIdx.x, w = t >> 6, lane = t & 63;
  const int l16 = lane & 15, g4 = lane >> 4;
  const int rowi = t & 63;
  const int cg   = (t >> 6) * 8;
  const int arow = t >> 2, aoff = (t & 3) * 8;
  f32x4 acc[4] = {};
  for (int k0 = 0; k0 < CO; k0 += 32) {
    float bv[8];
#pragma unroll
    for (int jj = 0; jj < 8; ++jj)
      bv[jj] = Wout[(size_t)(k0 + cg + jj) * CO + j0 + rowi];
    f16x8 a8 = *reinterpret_cast<const f16x8*>(
        ao + ((size_t)b * NTOK + n0 + arow) * CO + k0 + aoff);
    f16x4 blo, bhi;
#pragma unroll
    for (int jj = 0; jj < 4; ++jj) {
      blo[jj] = (f16)bv[jj];  bhi[jj] = (f16)bv[jj + 4];
    }
    *reinterpret_cast<f16x4*>(&Ws[rowi][cg])     = blo;
    *reinterpret_cast<f16x4*>(&Ws[rowi][cg + 4]) = bhi;
    f16x4 a8lo = __builtin_shufflevector(a8, a8, 0, 1, 2, 3);
    f16x4 a8hi = __builtin_shufflevector(a8, a8, 4, 5, 6, 7);
    *reinterpret_cast<f16x4*>(&Aos[arow][aoff])     = a8lo;
    *reinterpret_cast<f16x4*>(&Aos[arow][aoff + 4]) = a8hi;
    __syncthreads();
    f16x8 wf = ld8(&Ws[w * 16 + l16][g4 * 8]);
#pragma unroll
    for (int nf = 0; nf < 4; ++nf) {
      f16x8 af = ld8(&Aos[nf * 16 + l16][g4 * 8]);
      acc[nf] = mfma16(wf, af, acc[nf]);
    }
    __syncthreads();
  }
#pragma unroll
  for (int nf = 0; nf < 4; ++nf) {
#pragma unroll
    for (int r = 0; r < 4; ++r) {
      const int j = j0 + w * 16 + g4 * 4 + r;
      const int n = n0 + nf * 16 + l16;
      out[((size_t)b * CO + j) * NTOK + n] = acc[nf][r] + bout[j];
    }
  }
}

extern "C" void kernel_launch(void* const* d_in, const int* in_sizes, int n_in,
                              void* d_out, int out_size, void* d_ws, size_t ws_size,
                              hipStream_t stream) {
  const float* x    = (const float*)d_in[0];
  const float* Wqkv = (const float*)d_in[1];
  const float* bqkv = (const float*)d_in[2];
  const float* Wout = (const float*)d_in[3];
  const float* bout = (const float*)d_in[4];
  float* out = (float*)d_out;

  f16* qbuf = (f16*)d_ws;
  const size_t seg = (size_t)2 * NH * NTOK * DH;
  f16* kbuf = qbuf + seg;
  f16* vbuf = kbuf + seg;
  f16* ao   = vbuf + seg;

  qkv_kernel<<<dim3(NTOK / 64, C3 / 64, 2), 256, 0, stream>>>(x, Wqkv, bqkv, qbuf, kbuf, vbuf);
  attn_kernel<<<dim3(NTOK / 64, 16), 256, 0, stream>>>(qbuf, kbuf, vbuf, ao);
  proj_kernel<<<dim3(NTOK / 64, CO / 64, 2), 256, 0, stream>>>(ao, Wout, bout, out);
}

// Round 18
// 75.814 us; speedup vs baseline: 1.1037x; 1.1037x over previous
//
#include <hip/hip_runtime.h>

typedef _Float16 f16;
typedef _Float16 f16x2 __attribute__((ext_vector_type(2)));
typedef _Float16 f16x4 __attribute__((ext_vector_type(4)));
typedef _Float16 f16x8 __attribute__((ext_vector_type(8)));
typedef float f32x4 __attribute__((ext_vector_type(4)));
typedef float f32x16 __attribute__((ext_vector_type(16)));

#define NTOK 4096
#define CIN  256
#define C3   768
#define CO   256
#define NH   8
#define DH   32

__device__ __forceinline__ f32x4 mfma16(f16x8 a, f16x8 b, f32x4 c) {
  return __builtin_amdgcn_mfma_f32_16x16x32_f16(a, b, c, 0, 0, 0);
}
__device__ __forceinline__ f32x16 mfma32(f16x8 a, f16x8 b, f32x16 c) {
  return __builtin_amdgcn_mfma_f32_32x32x16_f16(a, b, c, 0, 0, 0);
}

// native 2^x (input already in log2 domain)
__device__ __forceinline__ float fexp2(float x) {
  float r; asm("v_exp_f32 %0, %1" : "=v"(r) : "v"(x)); return r;
}

__device__ __forceinline__ f16x2 cvt_pk(float lo, float hi) {
  return __builtin_bit_cast(f16x2, __builtin_amdgcn_cvt_pkrtz(lo, hi));
}

// RTZ pack for P (r6/r14/r15 passed with this exact pack at absmax 9.766e-4)
__device__ __forceinline__ f16x8 pack8(float a0, float a1, float a2, float a3,
                                       float a4, float a5, float a6, float a7) {
  f16x2 p0 = cvt_pk(a0, a1);
  f16x2 p1 = cvt_pk(a2, a3);
  f16x2 p2 = cvt_pk(a4, a5);
  f16x2 p3 = cvt_pk(a6, a7);
  f16x4 lo = __builtin_shufflevector(p0, p1, 0, 1, 2, 3);
  f16x4 hi = __builtin_shufflevector(p2, p3, 0, 1, 2, 3);
  return __builtin_shufflevector(lo, hi, 0, 1, 2, 3, 4, 5, 6, 7);
}

// two 8B LDS reads -> one A/B fragment (72B row stride keeps 8B alignment)
__device__ __forceinline__ f16x8 ld8(const f16* p) {
  f16x4 lo = *reinterpret_cast<const f16x4*>(p);
  f16x4 hi = *reinterpret_cast<const f16x4*>(p + 4);
  return __builtin_shufflevector(lo, hi, 0, 1, 2, 3, 4, 5, 6, 7);
}

// ---------------------------------------------------------------------------
// Kernel 1: qkv = x^T @ W_qkv + b_qkv. Staging identical to r12 (passing).
// OPERAND-SWAP for q/k blocks (j0 < 512, uniform per block): A=W-frag,
// B=x-frag -> C rows = j, cols = token. Each thread then owns 4 CONSECUTIVE
// d per sub-tile -> f16x4 stores (16 scalar 2B stores -> 4x8B). Dot products,
// k-order, bias, casts unchanged -> outputs bit-identical to r12.
// V-blocks (j0 >= 512) keep the old order/epilogue (vbuf is d-major).
// ---------------------------------------------------------------------------
__global__ __launch_bounds__(256) void qkv_kernel(
    const float* __restrict__ x, const float* __restrict__ Wqkv,
    const float* __restrict__ bqkv,
    f16* __restrict__ qbuf, f16* __restrict__ kbuf, f16* __restrict__ vbuf)
{
  __shared__ f16 As[64][36];   // [n][c]
  __shared__ f16 Bs[64][36];   // [j][c]
  const int b  = blockIdx.z;
  const int n0 = blockIdx.x * 64;
  const int j0 = blockIdx.y * 64;
  const int t  = threadIdx.x;
  const int w  = t >> 6;
  const int lane = t & 63;
  const int l16  = lane & 15;
  const int g4   = lane >> 4;
  const int rowi = t & 63;        // staging row (n or j); lane==row => coalesced
  const int cg   = (t >> 6) * 8;  // staging c-offset
  const bool vblk = (j0 >= 2 * CO);

  f32x4 acc[4] = {};
  for (int k0 = 0; k0 < CIN; k0 += 32) {
    float av[8], bv[8];
#pragma unroll
    for (int jj = 0; jj < 8; ++jj) {
      av[jj] = x[((size_t)b * CIN + (k0 + cg + jj)) * NTOK + n0 + rowi];
      bv[jj] = Wqkv[(size_t)(k0 + cg + jj) * C3 + j0 + rowi];
    }
    f16x4 alo, ahi, blo, bhi;
#pragma unroll
    for (int jj = 0; jj < 4; ++jj) {
      alo[jj] = (f16)av[jj];  ahi[jj] = (f16)av[jj + 4];
      blo[jj] = (f16)bv[jj];  bhi[jj] = (f16)bv[jj + 4];
    }
    *reinterpret_cast<f16x4*>(&As[rowi][cg])     = alo;
    *reinterpret_cast<f16x4*>(&As[rowi][cg + 4]) = ahi;
    *reinterpret_cast<f16x4*>(&Bs[rowi][cg])     = blo;
    *reinterpret_cast<f16x4*>(&Bs[rowi][cg + 4]) = bhi;
    __syncthreads();
    f16x8 bf = ld8(&Bs[w * 16 + l16][g4 * 8]);
#pragma unroll
    for (int mf = 0; mf < 4; ++mf) {
      f16x8 af = ld8(&As[mf * 16 + l16][g4 * 8]);
      acc[mf] = vblk ? mfma16(af, bf, acc[mf])    // rows=token, cols=j (old)
                     : mfma16(bf, af, acc[mf]);   // rows=j, cols=token (new)
    }
    __syncthreads();
  }

  if (!vblk) {
    // q/k: thread owns j = jb + r (4 consecutive), token n = n0+mf*16+l16
    const int jb = j0 + w * 16 + g4 * 4;
    const int s  = jb >> 8;                 // 0=q, 1=k (uniform per block)
    const int hh = (jb >> 5) & 7;
    const int d0 = jb & 31;
    const int bh = b * NH + hh;
    const float4 b4 = *reinterpret_cast<const float4*>(&bqkv[jb]);
    const float sc = (s == 0) ? 0.25503472f : 1.0f;  // log2(e)/sqrt(32); *1.0 exact
    f16* dst = (s == 0) ? qbuf : kbuf;
#pragma unroll
    for (int mf = 0; mf < 4; ++mf) {
      const int n = n0 + mf * 16 + l16;
      f16x4 st;
      st[0] = (f16)((acc[mf][0] + b4.x) * sc);
      st[1] = (f16)((acc[mf][1] + b4.y) * sc);
      st[2] = (f16)((acc[mf][2] + b4.z) * sc);
      st[3] = (f16)((acc[mf][3] + b4.w) * sc);
      *reinterpret_cast<f16x4*>(&dst[((size_t)bh * NTOK + n) * DH + d0]) = st;
    }
  } else {
    // v: old mapping; tiled + bit-2/3-swapped position (r12 verbatim)
    const int j  = j0 + w * 16 + l16;
    const int hh = (j >> 5) & 7;
    const int d  = j & 31;
    const float bias = bqkv[j];
    const int bh = b * NH + hh;
#pragma unroll
    for (int mf = 0; mf < 4; ++mf) {
#pragma unroll
      for (int r = 0; r < 4; ++r) {
        const int n = n0 + mf * 16 + g4 * 4 + r;
        const float v = acc[mf][r] + bias;
        const int g4p  = ((g4 & 1) << 1) | (g4 >> 1);
        const int tile = (n0 >> 5) + (mf >> 1);
        const int pos  = ((mf & 1) << 4) + g4p * 4 + r;
        vbuf[((size_t)bh * (NTOK / 32) + tile) * (DH * 32) + d * 32 + pos] = (f16)v;
        (void)n;
      }
    }
  }
}

// ---------------------------------------------------------------------------
// Kernel 2: flash attention — SOURCE BYTE-IDENTICAL to round-15 (57.3us,
// passing, absmax 9.766e-4). 2 q-rows/lane, 64 q-rows/wave, kv-split x2,
// additive LDS combine, XCD swizzle, monotonic depth-2 prefetch.
// ---------------------------------------------------------------------------
__global__ __launch_bounds__(256) void attn_kernel(
    const f16* __restrict__ qbuf, const f16* __restrict__ kbuf,
    const f16* __restrict__ vbuf, f16* __restrict__ ao)
{
  __shared__ float po_lds[2][64][33];   // [wq][q-in-wave][d] padded
  __shared__ float pl_lds[2][64];       // [wq][q-in-wave]

  // XCD swizzle: flat dispatch id -> XCD gets a contiguous 64-block chunk
  const int flat = blockIdx.x + (int)gridDim.x * blockIdx.y;   // 0..511
  const int nper = ((int)gridDim.x * (int)gridDim.y) >> 3;     // 64
  const int jj   = (flat & 7) * nper + (flat >> 3);
  const int bh = jj >> 5;
  const int q0 = (jj & 31) * 128;
  const int b = bh >> 3, h = bh & 7;
  const int t = threadIdx.x, w = t >> 6, lane = t & 63;
  const int wq = w & 1, z = w >> 1;
  const int l32 = lane & 31, hi = lane >> 5;
  const size_t kbase = (size_t)bh * NTOK * DH;

  const int qrowA = q0 + wq * 64 + l32;
  const int qrowB = qrowA + 32;
  const f16* qpA = qbuf + kbase + (size_t)qrowA * DH + hi * 8;
  const f16* qpB = qbuf + kbase + (size_t)qrowB * DH + hi * 8;
  const f16x8 qfA0 = *reinterpret_cast<const f16x8*>(qpA);
  const f16x8 qfA1 = *reinterpret_cast<const f16x8*>(qpA + 16);
  const f16x8 qfB0 = *reinterpret_cast<const f16x8*>(qpB);
  const f16x8 qfB1 = *reinterpret_cast<const f16x8*>(qpB + 16);

  const size_t zoff = (size_t)z * 65536;   // 64 tiles * 1024 elems
  const f16* kp = kbuf + kbase + zoff + (size_t)l32 * DH + hi * 8;
  const f16* vp = vbuf + kbase + zoff + (size_t)l32 * 32 + hi * 8;

  f32x16 oaccA = {}, oaccB = {};
  float lrunA = 0.f, lrunB = 0.f;
  const f32x16 zero = {};

  // prologue: tiles 0 and 1 in registers; s_cur for tile 0 (both q-halves)
  f16x8 kna, knb, vca, vcb, vna, vnb;
  f32x16 scurA, scurB;
  {
    f16x8 k0a = *reinterpret_cast<const f16x8*>(kp);
    f16x8 k0b = *reinterpret_cast<const f16x8*>(kp + 16);
    vca = *reinterpret_cast<const f16x8*>(vp);
    vcb = *reinterpret_cast<const f16x8*>(vp + 16);
    kna = *reinterpret_cast<const f16x8*>(kp + 1024);
    knb = *reinterpret_cast<const f16x8*>(kp + 1024 + 16);
    vna = *reinterpret_cast<const f16x8*>(vp + 1024);
    vnb = *reinterpret_cast<const f16x8*>(vp + 1024 + 16);
    scurA = mfma32(k0a, qfA0, zero);
    scurA = mfma32(k0b, qfA1, scurA);
    scurB = mfma32(k0a, qfB0, zero);
    scurB = mfma32(k0b, qfB1, scurB);
  }

  // running prefetch pointers (tile tt+2); tail overrun stays inside d_ws
  const f16* kfut = kp + 2048;
  const f16* vfut = vp + 2048;

#pragma unroll 2
  for (int tt = 0; tt < 64; ++tt) {
    // prefetch tile tt+2 (monotonic; tail values never consumed)
    f16x8 kpa = *reinterpret_cast<const f16x8*>(kfut);
    f16x8 kpb = *reinterpret_cast<const f16x8*>(kfut + 16);
    f16x8 vpa = *reinterpret_cast<const f16x8*>(vfut);
    f16x8 vpb = *reinterpret_cast<const f16x8*>(vfut + 16);
    kfut += 1024; vfut += 1024;

    // QK^T of tile tt+1, both q-halves (K regs loaded >=1 iteration ago)
    __builtin_amdgcn_s_setprio(1);
    f32x16 snextA = mfma32(kna, qfA0, zero);
    snextA = mfma32(knb, qfA1, snextA);
    f32x16 snextB = mfma32(kna, qfB0, zero);
    snextB = mfma32(knb, qfB1, snextB);
    __builtin_amdgcn_s_setprio(0);

    // softmax of tile tt, q-half A
    float eA[16];
#pragma unroll
    for (int i = 0; i < 16; ++i) eA[i] = fexp2(scurA[i]);
    {
      float a0 = eA[0] + eA[1],  a1 = eA[2] + eA[3];
      float a2 = eA[4] + eA[5],  a3 = eA[6] + eA[7];
      float a4 = eA[8] + eA[9],  a5 = eA[10] + eA[11];
      float a6 = eA[12] + eA[13], a7 = eA[14] + eA[15];
      lrunA += ((a0 + a1) + (a2 + a3)) + ((a4 + a5) + (a6 + a7));
    }
    f16x8 pbA0 = pack8(eA[0], eA[1], eA[2], eA[3], eA[4], eA[5], eA[6], eA[7]);
    f16x8 pbA1 = pack8(eA[8], eA[9], eA[10], eA[11], eA[12], eA[13], eA[14], eA[15]);

    // softmax of tile tt, q-half B
    float eB[16];
#pragma unroll
    for (int i = 0; i < 16; ++i) eB[i] = fexp2(scurB[i]);
    {
      float a0 = eB[0] + eB[1],  a1 = eB[2] + eB[3];
      float a2 = eB[4] + eB[5],  a3 = eB[6] + eB[7];
      float a4 = eB[8] + eB[9],  a5 = eB[10] + eB[11];
      float a6 = eB[12] + eB[13], a7 = eB[14] + eB[15];
      lrunB += ((a0 + a1) + (a2 + a3)) + ((a4 + a5) + (a6 + a7));
    }
    f16x8 pbB0 = pack8(eB[0], eB[1], eB[2], eB[3], eB[4], eB[5], eB[6], eB[7]);
    f16x8 pbB1 = pack8(eB[8], eB[9], eB[10], eB[11], eB[12], eB[13], eB[14], eB[15]);

    // PV of tile tt (V fragments reused for both q-halves)
    __builtin_amdgcn_s_setprio(1);
    oaccA = mfma32(vca, pbA0, oaccA);
    oaccA = mfma32(vcb, pbA1, oaccA);
    oaccB = mfma32(vca, pbB0, oaccB);
    oaccB = mfma32(vcb, pbB1, oaccB);
    __builtin_amdgcn_s_setprio(0);

    // rotate pipeline registers
    scurA = snextA; scurB = snextB;
    vca = vna; vcb = vnb;
    kna = kpa; knb = kpb;
    vna = vpa; vnb = vpb;
  }

  // per-half l totals (hi halves combined)
  const float ltotA = lrunA + __shfl_xor(lrunA, 32);
  const float ltotB = lrunB + __shfl_xor(lrunB, 32);

  // z=1 waves park raw partials in LDS
  if (z == 1) {
#pragma unroll
    for (int c4 = 0; c4 < 4; ++c4)
#pragma unroll
      for (int r = 0; r < 4; ++r) {
        po_lds[wq][l32][hi * 4 + c4 * 8 + r]      = oaccA[c4 * 4 + r];
        po_lds[wq][32 + l32][hi * 4 + c4 * 8 + r] = oaccB[c4 * 4 + r];
      }
    if (hi == 0) {
      pl_lds[wq][l32]      = ltotA;
      pl_lds[wq][32 + l32] = ltotB;
    }
  }
  __syncthreads();

  // z=0 waves combine (additive partials) and store both q-rows
  if (z == 0) {
    const float invA = 1.0f / (ltotA + pl_lds[wq][l32]);
    const float invB = 1.0f / (ltotB + pl_lds[wq][32 + l32]);
    f16* aopA = (f16*)ao + ((size_t)b * NTOK + qrowA) * CO + h * DH + hi * 4;
    f16* aopB = (f16*)ao + ((size_t)b * NTOK + qrowB) * CO + h * DH + hi * 4;
#pragma unroll
    for (int c4 = 0; c4 < 4; ++c4) {
      f16x4 stA, stB;
#pragma unroll
      for (int r = 0; r < 4; ++r) {
        stA[r] = (f16)((oaccA[c4 * 4 + r] + po_lds[wq][l32][hi * 4 + c4 * 8 + r]) * invA);
        stB[r] = (f16)((oaccB[c4 * 4 + r] + po_lds[wq][32 + l32][hi * 4 + c4 * 8 + r]) * invB);
      }
      *reinterpret_cast<f16x4*>(aopA + c4 * 8) = stA;
      *reinterpret_cast<f16x4*>(aopB + c4 * 8) = stB;
    }
  }
}

// ---------------------------------------------------------------------------
// Kernel 3: proj. OPERAND-SWAP: A=ao-frag (rows=token), B=W-frag (cols=j).
// Each thread owns 4 consecutive n for fixed j -> float4 stores (16 scalar
// f32 stores -> 4x16B). Values bit-identical to r12 (same dots + bias adds).
// ---------------------------------------------------------------------------
__global__ __launch_bounds__(256) void proj_kernel(
    const f16* __restrict__ ao, const float* __restrict__ Wout,
    const float* __restrict__ bout, float* __restrict__ out)
{
  __shared__ f16 Ws[64][36];    // [j][c]
  __shared__ f16 Aos[64][36];   // [n][c]
  const int b  = blockIdx.z;
  const int n0 = blockIdx.x * 64;
  const int j0 = blockIdx.y * 64;
  const int t = threadIdx.x, w = t >> 6, lane = t & 63;
  const int l16 = lane & 15, g4 = lane >> 4;
  const int rowi = t & 63;
  const int cg   = (t >> 6) * 8;
  const int arow = t >> 2, aoff = (t & 3) * 8;
  f32x4 acc[4] = {};
  for (int k0 = 0; k0 < CO; k0 += 32) {
    float bv[8];
#pragma unroll
    for (int jj = 0; jj < 8; ++jj)
      bv[jj] = Wout[(size_t)(k0 + cg + jj) * CO + j0 + rowi];
    f16x8 a8 = *reinterpret_cast<const f16x8*>(
        ao + ((size_t)b * NTOK + n0 + arow) * CO + k0 + aoff);
    f16x4 blo, bhi;
#pragma unroll
    for (int jj = 0; jj < 4; ++jj) {
      blo[jj] = (f16)bv[jj];  bhi[jj] = (f16)bv[jj + 4];
    }
    *reinterpret_cast<f16x4*>(&Ws[rowi][cg])     = blo;
    *reinterpret_cast<f16x4*>(&Ws[rowi][cg + 4]) = bhi;
    f16x4 a8lo = __builtin_shufflevector(a8, a8, 0, 1, 2, 3);
    f16x4 a8hi = __builtin_shufflevector(a8, a8, 4, 5, 6, 7);
    *reinterpret_cast<f16x4*>(&Aos[arow][aoff])     = a8lo;
    *reinterpret_cast<f16x4*>(&Aos[arow][aoff + 4]) = a8hi;
    __syncthreads();
    f16x8 wf = ld8(&Ws[w * 16 + l16][g4 * 8]);
#pragma unroll
    for (int nf = 0; nf < 4; ++nf) {
      f16x8 af = ld8(&Aos[nf * 16 + l16][g4 * 8]);
      acc[nf] = mfma16(af, wf, acc[nf]);   // swapped: rows=token, cols=j
    }
    __syncthreads();
  }
  // thread owns j = j0+w*16+l16 (fixed), n = n0+nf*16+g4*4+r (4 consecutive)
  const int j = j0 + w * 16 + l16;
  const float bj = bout[j];
#pragma unroll
  for (int nf = 0; nf < 4; ++nf) {
    float4 st;
    st.x = acc[nf][0] + bj;
    st.y = acc[nf][1] + bj;
    st.z = acc[nf][2] + bj;
    st.w = acc[nf][3] + bj;
    *reinterpret_cast<float4*>(
        &out[((size_t)b * CO + j) * NTOK + n0 + nf * 16 + g4 * 4]) = st;
  }
}

extern "C" void kernel_launch(void* const* d_in, const int* in_sizes, int n_in,
                              void* d_out, int out_size, void* d_ws, size_t ws_size,
                              hipStream_t stream) {
  const float* x    = (const float*)d_in[0];
  const float* Wqkv = (const float*)d_in[1];
  const float* bqkv = (const float*)d_in[2];
  const float* Wout = (const float*)d_in[3];
  const float* bout = (const float*)d_in[4];
  float* out = (float*)d_out;

  f16* qbuf = (f16*)d_ws;
  const size_t seg = (size_t)2 * NH * NTOK * DH;
  f16* kbuf = qbuf + seg;
  f16* vbuf = kbuf + seg;
  f16* ao   = vbuf + seg;

  qkv_kernel<<<dim3(NTOK / 64, C3 / 64, 2), 256, 0, stream>>>(x, Wqkv, bqkv, qbuf, kbuf, vbuf);
  attn_kernel<<<dim3(NTOK / 128, 16), 256, 0, stream>>>(qbuf, kbuf, vbuf, ao);
  proj_kernel<<<dim3(NTOK / 64, CO / 64, 2), 256, 0, stream>>>(ao, Wout, bout, out);
}